// Round 5
// baseline (16523.166 us; speedup 1.0000x reference)
//
#include <hip/hip_runtime.h>

typedef unsigned short ushort_t;
typedef __attribute__((ext_vector_type(8))) short short8;
typedef __attribute__((ext_vector_type(4))) float f32x4;

#define HH 64
#define TT 12
#define TOUT 12
#define CC 10
#define BNTOT 131072

// ---- per-wave LDS layout (floats) ----
#define WAVE_F 2608
#define O_HBUF 0      // 16 x 68 (stride 68: conflict-free b128 transpose)
#define O_XL   1088   // 16 x 28
#define O_HV   1536   // 16 x 28
#define O_W0   1984   // 16 x 12
#define O_VA   2176   // 16 x 12
#define O_NUM  2368   // 16 x 12
#define O_MR   2560
#define O_DR   2576
#define O_LV   2592

// bf16 hi/lo split helpers (truncation; 3-term product error ~2^-16 rel)
__device__ __forceinline__ ushort_t hib(float f){ return (ushort_t)(__float_as_uint(f) >> 16); }
__device__ __forceinline__ float ubf(ushort_t u){ return __uint_as_float(((unsigned)u) << 16); }
__device__ __forceinline__ ushort_t lob(float f){ float r = f - ubf(hib(f)); return hib(r); }

__device__ __forceinline__ float sigm(float x){
  return __builtin_amdgcn_rcpf(1.0f + __expf(-x));
}
__device__ __forceinline__ float tanh_f(float x){
  return 1.0f - 2.0f * __builtin_amdgcn_rcpf(1.0f + __expf(2.0f * x));
}

struct W {
  const float* ewih; const float* ewhh; const float* ebih; const float* ebhh;
  const float* dwih; const float* dwhh; const float* dbih; const float* dbhh;
  const float* l1w;  const float* l1b;  const float* l2w;  const float* l2b;
  const float* emb;
};

// ===================== prep: build frag-linear bf16 B-tiles =====================
// slot(c,ph,g,kt,term) = ((((c*2+ph)*17+g)*3+kt)*2+term), 512 ushorts per tile,
// element order: lane*8 + jj  (lane: col=lane&15, quad=lane>>4; k = 32*kt + quad*8 + jj)
// N-groups: g0-3 pre_r (j=16g+col), g4-7 pre_z, g8-11 gx_n, g12-15 gh_n, g16 v/hv.
// kt 0,1: h-rows (whh). kt 2 (aug): enc rows [wih_f0, wih_f1, bias_hi, bias_lo];
//   dec rows [dwih, bias_hi, bias_lo]. Bias rows live ONLY in term0 (A has exact 1.0s).
// hv tiles parked at (ph=0,g16,kt=0/1): B[k=2t+f'][col=2s+f] = (f'==f)*w2[s][t]; rows 24/25 = b2 hi/lo.
__device__ ushort_t prep_val(const W& w, int c, int ph, int g, int kt, int term, int col, int kk){
  if (g == 16 && ph == 0){
    if (kt == 2) return 0;
    int s_, f_;
    if (kt == 0){ s_ = col >> 1; f_ = col & 1; }
    else { if (col >= 8) return 0; s_ = 8 + (col >> 1); f_ = col & 1; }
    if (kk < 24){
      int t = kk >> 1, f2 = kk & 1;
      float v = (f2 == f_) ? w.l2w[c*144 + s_*12 + t] : 0.f;
      return term ? lob(v) : hib(v);
    }
    if (kk == 24) return term ? (ushort_t)0 : hib(w.l2b[c*12 + s_]);
    if (kk == 25) return term ? (ushort_t)0 : lob(w.l2b[c*12 + s_]);
    return 0;
  }
  if (kt < 2){
    int k = kt*32 + kk;
    float v;
    const float* whh = ph ? w.dwhh : w.ewhh;
    if (g < 4)       v = whh[c*12288 + (16*g + col)*64 + k];
    else if (g < 8)  v = whh[c*12288 + (64 + 16*(g-4) + col)*64 + k];
    else if (g < 12) return 0;                       // gx_n has no h-part
    else if (g < 16) v = whh[c*12288 + (128 + 16*(g-12) + col)*64 + k];
    else             v = (ph == 1 && col == 0) ? w.l1w[c*64 + k] : 0.f;
    return term ? lob(v) : hib(v);
  }
  // kt == 2 : aug rows
  int j = (g < 4)  ? 16*g + col
        : (g < 8)  ? 64 + 16*(g-4) + col
        : (g < 12) ? 128 + 16*(g-8) + col
        : (g < 16) ? 128 + 16*(g-12) + col : 0;
  if (ph == 0){
    if (kk == 0 || kk == 1){
      if (g >= 12) return 0;
      float v = w.ewih[c*384 + j*2 + kk];
      return term ? lob(v) : hib(v);
    }
    if (kk == 2 || kk == 3){
      if (term) return 0;
      float b;
      if (g < 8)       b = w.ebih[c*192 + j] + w.ebhh[c*192 + j];
      else if (g < 12) b = w.ebih[c*192 + j];
      else if (g < 16) b = w.ebhh[c*192 + j];
      else return 0;
      return (kk == 2) ? hib(b) : lob(b);
    }
    return 0;
  } else {
    if (kk == 0){
      if (g >= 12) return 0;
      float v = w.dwih[c*192 + j];
      return term ? lob(v) : hib(v);
    }
    if (kk == 1 || kk == 2){
      if (term) return 0;
      float b;
      if (g < 8)       b = w.dbih[c*192 + j] + w.dbhh[c*192 + j];
      else if (g < 12) b = w.dbih[c*192 + j];
      else if (g < 16) b = w.dbhh[c*192 + j];
      else             b = (col == 0) ? w.l1b[c] : 0.f;
      return (kk == 1) ? hib(b) : lob(b);
    }
    return 0;
  }
}

__global__ void prep_kernel(W w, ushort_t* __restrict__ fb){
  int s = blockIdx.x;
  int term = s & 1; int t1 = s >> 1;
  int kt = t1 % 3;  int t2 = t1 / 3;
  int g  = t2 % 17; int t3 = t2 / 17;
  int ph = t3 & 1;  int c  = t3 >> 1;
  #pragma unroll
  for (int u = 0; u < 2; ++u){
    int e = threadIdx.x*2 + u;
    int L = e >> 3, jj = e & 7;
    fb[(size_t)s*512 + e] = prep_val(w, c, ph, g, kt, term, L & 15, (L >> 4)*8 + jj);
  }
}

// ===================== main kernel =====================
#define MFMA16(A,B,C) __builtin_amdgcn_mfma_f32_16x16x32_bf16((A),(B),(C),0,0,0)

__device__ __forceinline__ void gemm40(const ushort_t* __restrict__ fb, int sb, int lane,
    const short8 ahi[2], const short8 alo[2], const short8& agh, const short8& agl,
    f32x4 acc[16])
{
  constexpr int PG[40] = {0,0,0,1,1,1,2,2,2,3,3,3,4,4,4,5,5,5,6,6,6,7,7,7,
                          8,9,10,11,12,12,12,13,13,13,14,14,14,15,15,15};
  constexpr int PK[40] = {0,1,2,0,1,2,0,1,2,0,1,2,0,1,2,0,1,2,0,1,2,0,1,2,
                          2,2,2,2,0,1,2,0,1,2,0,1,2,0,1,2};
  #pragma unroll
  for (int p = 0; p < 40; ++p){
    const int g = PG[p], kt = PK[p];
    const ushort_t* bp = fb + (size_t)(sb + (g*3 + kt)*2)*512 + lane*8;
    short8 bhi, blo;
    if (kt == 2){
      short8 z = {0,0,0,0,0,0,0,0};
      bhi = z; blo = z;
      if (lane < 16){ bhi = *(const short8*)bp; blo = *(const short8*)(bp + 512); }
    } else {
      bhi = *(const short8*)bp; blo = *(const short8*)(bp + 512);
    }
    const short8& Ah = (kt == 2) ? agh : ahi[kt];
    const short8& Al = (kt == 2) ? agl : alo[kt];
    acc[g] = MFMA16(Ah, bhi, acc[g]);
    acc[g] = MFMA16(Al, bhi, acc[g]);
    acc[g] = MFMA16(Ah, blo, acc[g]);
  }
}

__device__ __forceinline__ f32x4 v_gemm(const ushort_t* __restrict__ fb, int sb, int lane,
    const short8 ahi[2], const short8 alo[2], const short8& agh, const short8& agl)
{
  f32x4 acc = {0.f, 0.f, 0.f, 0.f};
  #pragma unroll
  for (int kt = 0; kt < 3; ++kt){
    const ushort_t* bp = fb + (size_t)(sb + (16*3 + kt)*2)*512 + lane*8;
    short8 bhi, blo;
    if (kt == 2){
      short8 z = {0,0,0,0,0,0,0,0};
      bhi = z; blo = z;
      if (lane < 16){ bhi = *(const short8*)bp; blo = *(const short8*)(bp + 512); }
    } else {
      bhi = *(const short8*)bp; blo = *(const short8*)(bp + 512);
    }
    const short8& Ah = (kt == 2) ? agh : ahi[kt];
    const short8& Al = (kt == 2) ? agl : alo[kt];
    acc = MFMA16(Ah, bhi, acc);
    acc = MFMA16(Al, bhi, acc);
    acc = MFMA16(Ah, blo, acc);
  }
  return acc;
}

// gates (C-layout) -> h_new regs + LDS transpose -> rebuild A-frags (hi/lo bf16)
__device__ __forceinline__ void gates_frags(const f32x4 acc[16], float hc[16],
    float* hb, int lane, short8 ahi[2], short8 alo[2])
{
  const int quad = lane >> 4, c15 = lane & 15;
  #pragma unroll
  for (int q = 0; q < 4; ++q){
    #pragma unroll
    for (int r = 0; r < 4; ++r){
      float pr = acc[q][r], pz = acc[4+q][r], gx = acc[8+q][r], gh = acc[12+q][r];
      float rr = sigm(pr), zz = sigm(pz);
      float nn = tanh_f(fmaf(rr, gh, gx));
      float hn = (1.0f - zz)*nn + zz*hc[q*4 + r];
      hc[q*4 + r] = hn;
      hb[(quad*4 + r)*68 + q*16 + c15] = hn;   // [m][j], stride 68
    }
  }
  const int m = c15, q8 = quad*8;
  #pragma unroll
  for (int kt = 0; kt < 2; ++kt){
    const f32x4* p = (const f32x4*)&hb[m*68 + kt*32 + q8];
    f32x4 a = p[0], b = p[1];
    float f[8] = {a[0], a[1], a[2], a[3], b[0], b[1], b[2], b[3]};
    #pragma unroll
    for (int j2 = 0; j2 < 8; ++j2){
      ahi[kt][j2] = (short)hib(f[j2]);
      alo[kt][j2] = (short)lob(f[j2]);
    }
  }
}

__global__ __launch_bounds__(256, 2) void rnn_mfma(
    const float* __restrict__ X, const float* __restrict__ emb,
    const ushort_t* __restrict__ fb, float* __restrict__ out)
{
  __shared__ __align__(16) float lds[4*WAVE_F];
  const int tid = threadIdx.x;
  const int wid = tid >> 6, lane = tid & 63;
  float* wl = lds + wid*WAVE_F;
  float* hb  = wl + O_HBUF;
  float* Xl  = wl + O_XL;
  float* hv  = wl + O_HV;
  float* w0  = wl + O_W0;
  float* va  = wl + O_VA;
  float* nmL = wl + O_NUM;
  float* mr  = wl + O_MR;
  float* dr  = wl + O_DR;
  float* lvb = wl + O_LV;
  const int wavebase = (blockIdx.x*4 + wid)*16;
  const int quad = lane >> 4, c15 = lane & 15;

  // stage X tile: Xl[m][2t+f], row stride 28
  for (int e = lane; e < 384; e += 64){
    int m = e / 24, k = e - m*24;
    Xl[m*28 + k] = X[(size_t)(wavebase + m)*24 + k];
  }
  // w0[m][o] = sum_t query[t]*emb[t][o]; init softmax state
  if (lane < 16){
    const int m = lane;
    #pragma unroll
    for (int o = 0; o < TOUT; ++o){
      float a = 0.f;
      #pragma unroll
      for (int t = 0; t < TT; ++t) a = fmaf(Xl[m*28 + 2*t], emb[t*TOUT + o], a);
      w0[m*12 + o] = a;
      nmL[m*12 + o] = 0.f;
    }
    mr[m] = -1e30f; dr[m] = 0.f;
  }

  // X-feature A-frags for hv GEMM (quad3 carries the exact-1 bias rows k=24,25)
  short8 z8 = {0,0,0,0,0,0,0,0};
  short8 axh = z8, axl = z8;
  if (quad < 3){
    const f32x4* p = (const f32x4*)&Xl[c15*28 + quad*8];
    f32x4 a = p[0], b = p[1];
    float f[8] = {a[0], a[1], a[2], a[3], b[0], b[1], b[2], b[3]};
    #pragma unroll
    for (int j2 = 0; j2 < 8; ++j2){
      axh[j2] = (short)hib(f[j2]);
      axl[j2] = (short)lob(f[j2]);
    }
  } else {
    axh[0] = (short)0x3F80; axh[1] = (short)0x3F80;
  }

  float lastv = 0.f;
  if (lane < 16) lastv = Xl[lane*28 + 22];   // Xr[m][11][0]

  #pragma unroll 1
  for (int c = 0; c < CC; ++c){
    const int sb0 = (c*2 + 0)*102;
    const int sb1 = (c*2 + 1)*102;

    // ---- hv GEMM: hv[m][2s+f] for all 12 encoder steps ----
    #pragma unroll
    for (int nt = 0; nt < 2; ++nt){
      f32x4 a = {0.f, 0.f, 0.f, 0.f};
      const ushort_t* bp = fb + (size_t)(sb0 + (16*3 + nt)*2)*512 + lane*8;
      short8 bhi = *(const short8*)bp, blo = *(const short8*)(bp + 512);
      a = MFMA16(axh, bhi, a);
      a = MFMA16(axl, bhi, a);
      a = MFMA16(axh, blo, a);
      if (nt == 0 || c15 < 8){
        #pragma unroll
        for (int r = 0; r < 4; ++r)
          hv[(quad*4 + r)*28 + nt*16 + c15] = a[r];
      }
    }

    // ---- encoder: h = 0 ----
    float hc[16];
    #pragma unroll
    for (int q = 0; q < 16; ++q) hc[q] = 0.f;
    short8 ahi[2], alo[2];
    ahi[0] = z8; ahi[1] = z8; alo[0] = z8; alo[1] = z8;
    short8 agh = z8, agl = z8;

    const int steps = 3 + c;
    #pragma unroll 1
    for (int j = 0; j < steps; ++j){
      agh = z8; agl = z8;
      if (lane < 16){
        float x0 = hv[lane*28 + 2*j], x1 = hv[lane*28 + 2*j + 1];
        agh[0] = (short)hib(x0); agh[1] = (short)hib(x1);
        agh[2] = (short)0x3F80;  agh[3] = (short)0x3F80;
        agl[0] = (short)lob(x0); agl[1] = (short)lob(x1);
      }
      f32x4 acc[16];
      #pragma unroll
      for (int g = 0; g < 16; ++g) acc[g] = (f32x4){0.f, 0.f, 0.f, 0.f};
      gemm40(fb, sb0, lane, ahi, alo, agh, agl, acc);
      gates_frags(acc, hc, hb, lane, ahi, alo);
    }

    // ---- decoder: 12 steps; v-column folded as N-tile 16 (l1b in bias rows) ----
    agh = z8; agl = z8;
    if (lane < 16){ agh[1] = (short)0x3F80; agh[2] = (short)0x3F80; }
    #pragma unroll 1
    for (int i = 0; i < TOUT; ++i){
      f32x4 accv = v_gemm(fb, sb1, lane, ahi, alo, agh, agl);  // v(h_i) = va[i-1]
      if (c15 == 0){
        #pragma unroll
        for (int r = 0; r < 4; ++r){
          lvb[quad*4 + r] = accv[r];
          if (i > 0) va[(quad*4 + r)*12 + (i-1)] = accv[r];
        }
      }
      if (lane < 16){
        float lv = (i == 0) ? lastv : lvb[lane];
        agh[0] = (short)hib(lv);
        agl[0] = (short)lob(lv);
      }
      f32x4 acc[16];
      #pragma unroll
      for (int g = 0; g < 16; ++g) acc[g] = (f32x4){0.f, 0.f, 0.f, 0.f};
      gemm40(fb, sb1, lane, ahi, alo, agh, agl, acc);
      gates_frags(acc, hc, hb, lane, ahi, alo);
    }
    // final v: va[11] = v(h_12)
    {
      f32x4 accv = v_gemm(fb, sb1, lane, ahi, alo, agh, agl);
      if (c15 == 0){
        #pragma unroll
        for (int r = 0; r < 4; ++r) va[(quad*4 + r)*12 + 11] = accv[r];
      }
    }

    // ---- online softmax update over configs ----
    if (lane < 16){
      const int m = lane;
      float l = 0.f;
      #pragma unroll
      for (int o = 0; o < TOUT; ++o) l = fmaf(w0[m*12 + o], va[m*12 + o], l);
      float mm = mr[m], dd = dr[m];
      float nmx = fmaxf(mm, l);
      float aa = __expf(mm - nmx);
      float ee = __expf(l - nmx);
      dr[m] = dd*aa + ee;
      #pragma unroll
      for (int o = 0; o < TOUT; ++o)
        nmL[m*12 + o] = nmL[m*12 + o]*aa + va[m*12 + o]*ee;
      mr[m] = nmx;
    }
  }

  if (lane < 16){
    const int m = lane;
    float inv = 1.0f / dr[m];
    #pragma unroll
    for (int o = 0; o < TOUT; ++o)
      out[(size_t)(wavebase + m)*12 + o] = nmL[m*12 + o]*inv;
  }
}

extern "C" void kernel_launch(void* const* d_in, const int* in_sizes, int n_in,
                              void* d_out, int out_size, void* d_ws, size_t ws_size,
                              hipStream_t stream) {
  // dict order: 0=A 1=X 2..14 = weights (resolved by size fingerprint)
  int iX = 1, iW = 2;
  for (int i = 0; i < n_in; ++i){
    if (in_sizes[i] == 3145728) iX = i;           // X
    if (in_sizes[i] == 3840)   { iW = i; break; } // enc_w_ih
  }
  W wp;
  wp.ewih = (const float*)d_in[iW + 0];
  wp.ewhh = (const float*)d_in[iW + 1];
  wp.ebih = (const float*)d_in[iW + 2];
  wp.ebhh = (const float*)d_in[iW + 3];
  wp.dwih = (const float*)d_in[iW + 4];
  wp.dwhh = (const float*)d_in[iW + 5];
  wp.dbih = (const float*)d_in[iW + 6];
  wp.dbhh = (const float*)d_in[iW + 7];
  wp.l1w  = (const float*)d_in[iW + 8];
  wp.l1b  = (const float*)d_in[iW + 9];
  wp.l2w  = (const float*)d_in[iW + 10];
  wp.l2b  = (const float*)d_in[iW + 11];
  wp.emb  = (const float*)d_in[iW + 12];

  ushort_t* fb = (ushort_t*)d_ws;   // 2040 tiles * 1KB = ~2.09 MB

  prep_kernel<<<2040, 256, 0, stream>>>(wp, fb);
  rnn_mfma<<<BNTOT / 64, 256, 0, stream>>>(
      (const float*)d_in[iX], wp.emb, fb, (float*)d_out);
}

// Round 6
// 12523.610 us; speedup vs baseline: 1.3194x; 1.3194x over previous
//
#include <hip/hip_runtime.h>

typedef unsigned short ushort_t;
typedef __attribute__((ext_vector_type(8))) short short8;
typedef __attribute__((ext_vector_type(4))) float f32x4;

#define HH 64
#define TT 12
#define TOUT 12
#define CC 10
#define BNTOT 131072

// bf16 hi/lo split helpers (truncation; 3-term product error ~2^-16 rel)
__device__ __forceinline__ ushort_t hib(float f){ return (ushort_t)(__float_as_uint(f) >> 16); }
__device__ __forceinline__ float ubf(ushort_t u){ return __uint_as_float(((unsigned)u) << 16); }
__device__ __forceinline__ ushort_t lob(float f){ float r = f - ubf(hib(f)); return hib(r); }

__device__ __forceinline__ float sigm(float x){
  return __builtin_amdgcn_rcpf(1.0f + __expf(-x));
}
__device__ __forceinline__ float tanh_f(float x){
  return 1.0f - 2.0f * __builtin_amdgcn_rcpf(1.0f + __expf(2.0f * x));
}

struct W {
  const float* ewih; const float* ewhh; const float* ebih; const float* ebhh;
  const float* dwih; const float* dwhh; const float* dbih; const float* dbhh;
  const float* l1w;  const float* l1b;  const float* l2w;  const float* l2b;
  const float* emb;
};

// ===================== prep: UNCHANGED from round 5 (verified) =====================
// slot(c,ph,g,kt,term) = ((((c*2+ph)*17+g)*3+kt)*2+term), 512 ushorts per tile,
// element order: lane*8 + jj  (lane: col=lane&15, quad=lane>>4; k = 32*kt + quad*8 + jj)
__device__ ushort_t prep_val(const W& w, int c, int ph, int g, int kt, int term, int col, int kk){
  if (g == 16 && ph == 0){
    if (kt == 2) return 0;
    int s_, f_;
    if (kt == 0){ s_ = col >> 1; f_ = col & 1; }
    else { if (col >= 8) return 0; s_ = 8 + (col >> 1); f_ = col & 1; }
    if (kk < 24){
      int t = kk >> 1, f2 = kk & 1;
      float v = (f2 == f_) ? w.l2w[c*144 + s_*12 + t] : 0.f;
      return term ? lob(v) : hib(v);
    }
    if (kk == 24) return term ? (ushort_t)0 : hib(w.l2b[c*12 + s_]);
    if (kk == 25) return term ? (ushort_t)0 : lob(w.l2b[c*12 + s_]);
    return 0;
  }
  if (kt < 2){
    int k = kt*32 + kk;
    float v;
    const float* whh = ph ? w.dwhh : w.ewhh;
    if (g < 4)       v = whh[c*12288 + (16*g + col)*64 + k];
    else if (g < 8)  v = whh[c*12288 + (64 + 16*(g-4) + col)*64 + k];
    else if (g < 12) return 0;
    else if (g < 16) v = whh[c*12288 + (128 + 16*(g-12) + col)*64 + k];
    else             v = (ph == 1 && col == 0) ? w.l1w[c*64 + k] : 0.f;
    return term ? lob(v) : hib(v);
  }
  int j = (g < 4)  ? 16*g + col
        : (g < 8)  ? 64 + 16*(g-4) + col
        : (g < 12) ? 128 + 16*(g-8) + col
        : (g < 16) ? 128 + 16*(g-12) + col : 0;
  if (ph == 0){
    if (kk == 0 || kk == 1){
      if (g >= 12) return 0;
      float v = w.ewih[c*384 + j*2 + kk];
      return term ? lob(v) : hib(v);
    }
    if (kk == 2 || kk == 3){
      if (term) return 0;
      float b;
      if (g < 8)       b = w.ebih[c*192 + j] + w.ebhh[c*192 + j];
      else if (g < 12) b = w.ebih[c*192 + j];
      else if (g < 16) b = w.ebhh[c*192 + j];
      else return 0;
      return (kk == 2) ? hib(b) : lob(b);
    }
    return 0;
  } else {
    if (kk == 0){
      if (g >= 12) return 0;
      float v = w.dwih[c*192 + j];
      return term ? lob(v) : hib(v);
    }
    if (kk == 1 || kk == 2){
      if (term) return 0;
      float b;
      if (g < 8)       b = w.dbih[c*192 + j] + w.dbhh[c*192 + j];
      else if (g < 12) b = w.dbih[c*192 + j];
      else if (g < 16) b = w.dbhh[c*192 + j];
      else             b = (col == 0) ? w.l1b[c] : 0.f;
      return (kk == 1) ? hib(b) : lob(b);
    }
    return 0;
  }
}

__global__ void prep_kernel(W w, ushort_t* __restrict__ fb){
  int s = blockIdx.x;
  int term = s & 1; int t1 = s >> 1;
  int kt = t1 % 3;  int t2 = t1 / 3;
  int g  = t2 % 17; int t3 = t2 / 17;
  int ph = t3 & 1;  int c  = t3 >> 1;
  #pragma unroll
  for (int u = 0; u < 2; ++u){
    int e = threadIdx.x*2 + u;
    int L = e >> 3, jj = e & 7;
    fb[(size_t)s*512 + e] = prep_val(w, c, ph, g, kt, term, L & 15, (L >> 4)*8 + jj);
  }
}

// ===================== main kernel =====================
#define MFMA16(A,B,C) __builtin_amdgcn_mfma_f32_16x16x32_bf16((A),(B),(C),0,0,0)

// one GRU step: aug in fp32 VALU, h-part via MFMA (hi-tiles from LDS, lo from global)
__device__ __forceinline__ void run_step(
    const float x0[4], const float x1[4],
    const ushort_t* __restrict__ tiles, const ushort_t* __restrict__ fblo,
    const float* __restrict__ auw,
    float hc[16], short8 ahi[2], short8 alo[2], float* hb,
    int c15, int quad, int lane8)
{
  f32x4 acc[12];
  // aug init: a0-3 pre_r (j=16a+c15), a4-7 pre_z (64+...), a8-11 gh_n bias only
  #pragma unroll
  for (int a = 0; a < 8; ++a){
    const int j = (a & 3)*16 + c15 + (a >= 4 ? 64 : 0);
    const float w0 = auw[j], w1 = auw[192 + j], bb = auw[384 + j];
    #pragma unroll
    for (int r = 0; r < 4; ++r)
      acc[a][r] = fmaf(x0[r], w0, fmaf(x1[r], w1, bb));
  }
  #pragma unroll
  for (int a = 8; a < 12; ++a){
    const float bb = auw[576 + (a - 8)*16 + c15];
    #pragma unroll
    for (int r = 0; r < 4; ++r) acc[a][r] = bb;
  }
  // h-part MFMAs: 12 groups x 2 kt x 3 terms
  #pragma unroll
  for (int a = 0; a < 12; ++a){
    const int g = a < 8 ? a : a + 4;
    #pragma unroll
    for (int kt = 0; kt < 2; ++kt){
      const short8 bhi = *(const short8*)(tiles + (a*2 + kt)*512 + lane8);
      const short8 blo = *(const short8*)(fblo + (size_t)((g*3 + kt)*2 + 1)*512 + lane8);
      acc[a] = MFMA16(ahi[kt], bhi, acc[a]);
      acc[a] = MFMA16(alo[kt], bhi, acc[a]);
      acc[a] = MFMA16(ahi[kt], blo, acc[a]);
    }
  }
  // gates (gx_n inline fp32) + transpose via hb (stride 68, round-5 verified)
  #pragma unroll
  for (int q = 0; q < 4; ++q){
    #pragma unroll
    for (int r = 0; r < 4; ++r){
      const float pr = acc[q][r], pz = acc[4 + q][r], gh = acc[8 + q][r];
      const int j = 128 + q*16 + c15;
      const float gx = fmaf(x0[r], auw[j], fmaf(x1[r], auw[192 + j], auw[384 + j]));
      const float rr = sigm(pr), zz = sigm(pz);
      const float nn = tanh_f(fmaf(rr, gh, gx));
      const float hn = (1.0f - zz)*nn + zz*hc[q*4 + r];
      hc[q*4 + r] = hn;
      hb[(quad*4 + r)*68 + q*16 + c15] = hn;
    }
  }
  const int m = c15, q8 = quad*8;
  #pragma unroll
  for (int kt = 0; kt < 2; ++kt){
    const f32x4* p = (const f32x4*)&hb[m*68 + kt*32 + q8];
    f32x4 a = p[0], b = p[1];
    float f[8] = {a[0], a[1], a[2], a[3], b[0], b[1], b[2], b[3]};
    #pragma unroll
    for (int j2 = 0; j2 < 8; ++j2){
      ahi[kt][j2] = (short)hib(f[j2]);
      alo[kt][j2] = (short)lob(f[j2]);
    }
  }
}

__global__ __launch_bounds__(256, 2) void rnn_mfma2(
    const float* __restrict__ X, W wp,
    const ushort_t* __restrict__ fb, float* __restrict__ out)
{
  __shared__ __align__(16) ushort_t tiles_s[26*512];   // 26 KB staged hi tiles
  __shared__ __align__(16) float auw_s[640];           // AW0/AW1/AB[192*3] + ABH[64]
  __shared__ __align__(16) float wbuf_s[4*1744];       // per-wave hb/hv/va/lvb

  const int tid = threadIdx.x;
  const int wid = tid >> 6, lane = tid & 63;
  const int quad = lane >> 4, c15 = lane & 15;
  const int lane8 = lane*8;
  float* wl  = wbuf_s + wid*1744;
  float* hb  = wl;                 // 16*68
  float* hv  = wl + 1088;          // 16*28
  float* va  = wl + 1536;          // 16*12
  float* lvb = wl + 1728;          // 16
  const int wavebase = (blockIdx.x*4 + wid)*16;

  // ---- X row -> registers: lane holds row m=c15, elements [quad*8, quad*8+8) ----
  float xr[8];
  if (quad < 3){
    const float* xp = X + (size_t)(wavebase + c15)*24 + quad*8;
    f32x4 p0 = *(const f32x4*)xp, p1 = *(const f32x4*)(xp + 4);
    xr[0]=p0[0]; xr[1]=p0[1]; xr[2]=p0[2]; xr[3]=p0[3];
    xr[4]=p1[0]; xr[5]=p1[1]; xr[6]=p1[2]; xr[7]=p1[3];
  } else {
    #pragma unroll
    for (int i = 0; i < 8; ++i) xr[i] = 0.f;
  }
  const float lastv = X[(size_t)(wavebase + c15)*24 + 22];   // Xr[m][11][0]

  // w0[o] = sum_t query[t]*emb[t][o]; quad q holds t in [4q,4q+4) -> shfl reduce
  float w0[TOUT];
  #pragma unroll
  for (int o = 0; o < TOUT; ++o) w0[o] = 0.f;
  if (quad < 3){
    #pragma unroll
    for (int tt = 0; tt < 4; ++tt){
      const int t = quad*4 + tt;
      const float qv = xr[2*tt];
      #pragma unroll
      for (int o = 0; o < TOUT; ++o) w0[o] = fmaf(qv, wp.emb[t*TOUT + o], w0[o]);
    }
  }
  #pragma unroll
  for (int o = 0; o < TOUT; ++o){
    w0[o] += __shfl_xor(w0[o], 16, 64);
    w0[o] += __shfl_xor(w0[o], 32, 64);
  }

  // A-frags for hv GEMM (quad3 = exact-1 bias rows k=24,25)
  short8 z8 = {0,0,0,0,0,0,0,0};
  short8 axh = z8, axl = z8;
  if (quad < 3){
    #pragma unroll
    for (int j2 = 0; j2 < 8; ++j2){
      axh[j2] = (short)hib(xr[j2]);
      axl[j2] = (short)lob(xr[j2]);
    }
  } else {
    axh[0] = (short)0x3F80; axh[1] = (short)0x3F80;
  }

  // online softmax state (per-lane, m = c15; all quads redundantly compute)
  float msx = -1e30f, dsum = 0.f;
  float num[TOUT];
  #pragma unroll
  for (int o = 0; o < TOUT; ++o) num[o] = 0.f;

  #pragma unroll 1
  for (int c = 0; c < CC; ++c){
    const int sb0 = (c*2 + 0)*102;
    const int sb1 = (c*2 + 1)*102;
    const ushort_t* fblo0 = fb + (size_t)sb0*512;
    const ushort_t* fblo1 = fb + (size_t)sb1*512;
    const float l1b = wp.l1b[c];

    // ======== encoder phase ========
    __syncthreads();
    // stage 24 hi tiles + aug arrays (enc)
    for (int ch = tid; ch < 24*64; ch += 256){
      const int tile = ch >> 6, off = (ch & 63)*8;
      const int a = tile >> 1, kt = tile & 1;
      const int g = a < 8 ? a : a + 4;
      *(short8*)(tiles_s + tile*512 + off) =
          *(const short8*)(fb + (size_t)(sb0 + (g*3 + kt)*2)*512 + off);
    }
    for (int j = tid; j < 192; j += 256){
      auw_s[j]       = wp.ewih[c*384 + 2*j];
      auw_s[192 + j] = wp.ewih[c*384 + 2*j + 1];
      auw_s[384 + j] = wp.ebih[c*192 + j] + (j < 128 ? wp.ebhh[c*192 + j] : 0.f);
      if (j >= 128) auw_s[576 + (j - 128)] = wp.ebhh[c*192 + j];
    }
    __syncthreads();

    // hv GEMM (global g16 tiles, round-5 verified)
    #pragma unroll
    for (int nt = 0; nt < 2; ++nt){
      f32x4 a = {0.f, 0.f, 0.f, 0.f};
      const ushort_t* bp = fb + (size_t)(sb0 + (16*3 + nt)*2)*512 + lane8;
      short8 bhi = *(const short8*)bp, blo = *(const short8*)(bp + 512);
      a = MFMA16(axh, bhi, a);
      a = MFMA16(axl, bhi, a);
      a = MFMA16(axh, blo, a);
      if (nt == 0 || c15 < 8){
        #pragma unroll
        for (int r = 0; r < 4; ++r)
          hv[(quad*4 + r)*28 + nt*16 + c15] = a[r];
      }
    }

    float hc[16];
    #pragma unroll
    for (int q = 0; q < 16; ++q) hc[q] = 0.f;
    short8 ahi[2], alo[2];
    ahi[0] = z8; ahi[1] = z8; alo[0] = z8; alo[1] = z8;

    const int steps = 3 + c;
    #pragma unroll 1
    for (int j = 0; j < steps; ++j){
      float x0[4], x1[4];
      #pragma unroll
      for (int r = 0; r < 4; ++r){
        x0[r] = hv[(quad*4 + r)*28 + 2*j];
        x1[r] = hv[(quad*4 + r)*28 + 2*j + 1];
      }
      run_step(x0, x1, tiles_s, fblo0, auw_s, hc, ahi, alo, hb, c15, quad, lane8);
    }

    // ======== decoder phase ========
    __syncthreads();
    for (int ch = tid; ch < 26*64; ch += 256){
      const int tile = ch >> 6, off = (ch & 63)*8;
      int g, kt;
      if (tile < 24){ const int a = tile >> 1; kt = tile & 1; g = a < 8 ? a : a + 4; }
      else          { g = 16; kt = tile - 24; }
      *(short8*)(tiles_s + tile*512 + off) =
          *(const short8*)(fb + (size_t)(sb1 + (g*3 + kt)*2)*512 + off);
    }
    for (int j = tid; j < 192; j += 256){
      auw_s[j]       = wp.dwih[c*192 + j];
      auw_s[192 + j] = 0.f;
      auw_s[384 + j] = wp.dbih[c*192 + j] + (j < 128 ? wp.dbhh[c*192 + j] : 0.f);
      if (j >= 128) auw_s[576 + (j - 128)] = wp.dbhh[c*192 + j];
    }
    __syncthreads();

    if (quad == 0) lvb[c15] = lastv;

    const float zx1[4] = {0.f, 0.f, 0.f, 0.f};
    #pragma unroll 1
    for (int i = 0; i < TOUT; ++i){
      if (i > 0){
        // v(h_i): staged l1w hi tiles + global lo + fp32 l1b
        f32x4 accv = {l1b, l1b, l1b, l1b};
        #pragma unroll
        for (int kt = 0; kt < 2; ++kt){
          const short8 bhi = *(const short8*)(tiles_s + (24 + kt)*512 + lane8);
          const short8 blo = *(const short8*)(fblo1 + (size_t)((48 + kt)*2 + 1)*512 + lane8);
          accv = MFMA16(ahi[kt], bhi, accv);
          accv = MFMA16(alo[kt], bhi, accv);
          accv = MFMA16(ahi[kt], blo, accv);
        }
        if (c15 == 0){
          #pragma unroll
          for (int r = 0; r < 4; ++r){
            va[(quad*4 + r)*12 + (i - 1)] = accv[r];
            lvb[quad*4 + r] = accv[r];
          }
        }
      }
      float x0[4];
      #pragma unroll
      for (int r = 0; r < 4; ++r) x0[r] = lvb[quad*4 + r];
      run_step(x0, zx1, tiles_s, fblo1, auw_s, hc, ahi, alo, hb, c15, quad, lane8);
    }
    {
      f32x4 accv = {l1b, l1b, l1b, l1b};
      #pragma unroll
      for (int kt = 0; kt < 2; ++kt){
        const short8 bhi = *(const short8*)(tiles_s + (24 + kt)*512 + lane8);
        const short8 blo = *(const short8*)(fblo1 + (size_t)((48 + kt)*2 + 1)*512 + lane8);
        accv = MFMA16(ahi[kt], bhi, accv);
        accv = MFMA16(alo[kt], bhi, accv);
        accv = MFMA16(ahi[kt], blo, accv);
      }
      if (c15 == 0){
        #pragma unroll
        for (int r = 0; r < 4; ++r) va[(quad*4 + r)*12 + 11] = accv[r];
      }
    }

    // online softmax update (per-lane, m=c15)
    {
      float l = 0.f;
      #pragma unroll
      for (int o = 0; o < TOUT; ++o) l = fmaf(w0[o], va[c15*12 + o], l);
      const float nmx = fmaxf(msx, l);
      const float aa = __expf(msx - nmx);
      const float ee = __expf(l - nmx);
      dsum = dsum*aa + ee;
      #pragma unroll
      for (int o = 0; o < TOUT; ++o) num[o] = num[o]*aa + va[c15*12 + o]*ee;
      msx = nmx;
    }
  }

  if (quad == 0){
    const float inv = 1.0f / dsum;
    #pragma unroll
    for (int o = 0; o < TOUT; ++o)
      out[(size_t)(wavebase + c15)*12 + o] = num[o]*inv;
  }
}

extern "C" void kernel_launch(void* const* d_in, const int* in_sizes, int n_in,
                              void* d_out, int out_size, void* d_ws, size_t ws_size,
                              hipStream_t stream) {
  int iX = 1, iW = 2;
  for (int i = 0; i < n_in; ++i){
    if (in_sizes[i] == 3145728) iX = i;
    if (in_sizes[i] == 3840)   { iW = i; break; }
  }
  W wp;
  wp.ewih = (const float*)d_in[iW + 0];
  wp.ewhh = (const float*)d_in[iW + 1];
  wp.ebih = (const float*)d_in[iW + 2];
  wp.ebhh = (const float*)d_in[iW + 3];
  wp.dwih = (const float*)d_in[iW + 4];
  wp.dwhh = (const float*)d_in[iW + 5];
  wp.dbih = (const float*)d_in[iW + 6];
  wp.dbhh = (const float*)d_in[iW + 7];
  wp.l1w  = (const float*)d_in[iW + 8];
  wp.l1b  = (const float*)d_in[iW + 9];
  wp.l2w  = (const float*)d_in[iW + 10];
  wp.l2b  = (const float*)d_in[iW + 11];
  wp.emb  = (const float*)d_in[iW + 12];

  ushort_t* fb = (ushort_t*)d_ws;

  prep_kernel<<<2040, 256, 0, stream>>>(wp, fb);
  rnn_mfma2<<<BNTOT / 64, 256, 0, stream>>>(
      (const float*)d_in[iX], wp, fb, (float*)d_out);
}